// Round 1
// baseline (513.407 us; speedup 1.0000x reference)
//
#include <hip/hip_runtime.h>

#define S_LEN 2048
#define D_MODEL 1024
#define NH 16
#define NKV 4
#define HD 64
#define QCOLS (NH * HD)     // 1024
#define KVCOLS (NKV * HD)   // 256

// ---------------------------------------------------------------------------
// Kernel 1: QKV projection GEMM.  C[2048 x 1536] = x[2048 x 1024] @ [Wq|Wk|Wv]
// 64x64 tile / block, BK=32, 256 threads, 4x4 micro-tile per thread.
// Epilogue scatters into head-major Q[NH][S][HD], K[NKV][S][HD], V[NKV][S][HD].
// ---------------------------------------------------------------------------
__global__ __launch_bounds__(256) void gemm_qkv_kernel(
    const float* __restrict__ x, const float* __restrict__ Wq,
    const float* __restrict__ Wk, const float* __restrict__ Wv,
    float* __restrict__ Qws, float* __restrict__ Kws, float* __restrict__ Vws)
{
    __shared__ float At[32][68];   // [k][m]  (transposed A tile)
    __shared__ float Bs[32][68];   // [k][n]

    const int t   = threadIdx.x;
    const int m0  = blockIdx.x * 64;
    const int n0g = blockIdx.y * 64;

    const float* Bmat; int ldb, n0;
    if (n0g < QCOLS)                { Bmat = Wq; ldb = QCOLS;  n0 = n0g; }
    else if (n0g < QCOLS + KVCOLS)  { Bmat = Wk; ldb = KVCOLS; n0 = n0g - QCOLS; }
    else                            { Bmat = Wv; ldb = KVCOLS; n0 = n0g - QCOLS - KVCOLS; }

    const int tr = t >> 4, tc = t & 15;
    const int ar = t >> 3;            // 0..31
    const int ak = (t & 7) * 4;       // 0..28
    const int bk = t >> 3;            // 0..31
    const int bn = (t & 7) * 8;       // 0..56

    float acc[4][4] = {{0.f}};

    for (int k0 = 0; k0 < D_MODEL; k0 += 32) {
        // stage A (transposed into [k][m])
        #pragma unroll
        for (int rr = 0; rr < 2; ++rr) {
            const int row = ar + rr * 32;
            float4 a = *(const float4*)(x + (size_t)(m0 + row) * D_MODEL + k0 + ak);
            At[ak + 0][row] = a.x; At[ak + 1][row] = a.y;
            At[ak + 2][row] = a.z; At[ak + 3][row] = a.w;
        }
        // stage B
        {
            const float* src = Bmat + (size_t)(k0 + bk) * ldb + n0 + bn;
            float4 b0 = *(const float4*)(src);
            float4 b1 = *(const float4*)(src + 4);
            *(float4*)&Bs[bk][bn]     = b0;
            *(float4*)&Bs[bk][bn + 4] = b1;
        }
        __syncthreads();

        #pragma unroll
        for (int kk = 0; kk < 32; ++kk) {
            float4 a = *(const float4*)&At[kk][tr * 4];
            float4 b = *(const float4*)&Bs[kk][tc * 4];
            const float av[4] = {a.x, a.y, a.z, a.w};
            const float bv[4] = {b.x, b.y, b.z, b.w};
            #pragma unroll
            for (int i = 0; i < 4; ++i)
                #pragma unroll
                for (int j = 0; j < 4; ++j)
                    acc[i][j] = fmaf(av[i], bv[j], acc[i][j]);
        }
        __syncthreads();
    }

    // epilogue: scatter into head-major layouts
    if (n0g < QCOLS) {
        const int col = n0g + tc * 4;
        const int h = col >> 6, d = col & 63;
        #pragma unroll
        for (int i = 0; i < 4; ++i) {
            float4 o = {acc[i][0], acc[i][1], acc[i][2], acc[i][3]};
            *(float4*)(Qws + ((size_t)h * S_LEN + m0 + tr * 4 + i) * HD + d) = o;
        }
    } else if (n0g < QCOLS + KVCOLS) {
        const int col = n0g - QCOLS + tc * 4;
        const int h = col >> 6, d = col & 63;
        #pragma unroll
        for (int i = 0; i < 4; ++i) {
            float4 o = {acc[i][0], acc[i][1], acc[i][2], acc[i][3]};
            *(float4*)(Kws + ((size_t)h * S_LEN + m0 + tr * 4 + i) * HD + d) = o;
        }
    } else {
        const int col = n0g - QCOLS - KVCOLS + tc * 4;
        const int h = col >> 6, d = col & 63;
        #pragma unroll
        for (int i = 0; i < 4; ++i) {
            float4 o = {acc[i][0], acc[i][1], acc[i][2], acc[i][3]};
            *(float4*)(Vws + ((size_t)h * S_LEN + m0 + tr * 4 + i) * HD + d) = o;
        }
    }
}

// ---------------------------------------------------------------------------
// Kernel 2: RoPE in-place on Q (NH heads) and K (NKV heads).
// One thread per (head, s, d<32) rotation pair.  Total (NH+NKV)*S*32 threads.
// ---------------------------------------------------------------------------
__global__ __launch_bounds__(256) void rope_kernel(
    float* __restrict__ Q, float* __restrict__ K,
    const float* __restrict__ cosT, const float* __restrict__ sinT)
{
    const int idx  = blockIdx.x * 256 + threadIdx.x;
    const int d    = idx & 31;
    const int s    = (idx >> 5) & (S_LEN - 1);
    const int head = idx >> 16;                    // 32*2048 = 2^16
    const float c  = cosT[s * 32 + d];
    const float sn = sinT[s * 32 + d];
    float* base = (head < NH) ? (Q + ((size_t)head * S_LEN + s) * HD)
                              : (K + ((size_t)(head - NH) * S_LEN + s) * HD);
    const float t1 = base[d], t2 = base[d + 32];
    base[d]      = t1 * c - t2 * sn;
    base[d + 32] = t2 * c + t1 * sn;
}

// ---------------------------------------------------------------------------
// Kernel 3: causal flash attention, fp32.
// Grid (S/64, NH); block 256.  Per block: 64-query tile of one head.
// Thread (tr,tc) in 16x16: score rows tr*4..+3, score cols {tc,tc+16,tc+32,tc+48};
// output rows tr*4..+3, dims tc*4..+3.  16-lane shuffle row reductions.
// ---------------------------------------------------------------------------
__global__ __launch_bounds__(256) void attn_kernel(
    const float* __restrict__ Q, const float* __restrict__ K,
    const float* __restrict__ V, float* __restrict__ Aout)
{
    __shared__ float Qs[64][HD + 4];
    __shared__ float Ks[64][HD + 4];
    __shared__ float Vs[64][HD + 4];
    __shared__ float Ps[64][HD + 4];

    const int t   = threadIdx.x;
    const int h   = blockIdx.y;
    const int q0  = blockIdx.x * 64;
    const int kvh = h >> 2;

    const float* Qh = Q + ((size_t)h * S_LEN + q0) * HD;
    const float* Kh = K + (size_t)kvh * S_LEN * HD;
    const float* Vh = V + (size_t)kvh * S_LEN * HD;

    const int sr = t >> 2;          // staging row 0..63
    const int sc = (t & 3) * 16;    // staging col base

    #pragma unroll
    for (int u = 0; u < 4; ++u)
        *(float4*)&Qs[sr][sc + u * 4] =
            *(const float4*)(Qh + (size_t)sr * HD + sc + u * 4);

    const int tr = t >> 4;   // 0..15
    const int tc = t & 15;   // 0..15

    float m_i[4], l_i[4], Oacc[4][4];
    #pragma unroll
    for (int i = 0; i < 4; ++i) {
        m_i[i] = -3.0e38f; l_i[i] = 0.f;
        #pragma unroll
        for (int j = 0; j < 4; ++j) Oacc[i][j] = 0.f;
    }

    const float scale  = 0.125f;   // 1/sqrt(64)
    const int   ntiles = q0 / 64 + 1;

    for (int tile = 0; tile < ntiles; ++tile) {
        const int j0 = tile * 64;
        #pragma unroll
        for (int u = 0; u < 4; ++u) {
            *(float4*)&Ks[sr][sc + u * 4] =
                *(const float4*)(Kh + (size_t)(j0 + sr) * HD + sc + u * 4);
            *(float4*)&Vs[sr][sc + u * 4] =
                *(const float4*)(Vh + (size_t)(j0 + sr) * HD + sc + u * 4);
        }
        __syncthreads();

        // S = Q K^T  (4x4 per thread)
        float s[4][4] = {{0.f}};
        #pragma unroll
        for (int d = 0; d < HD; d += 4) {
            float4 qv[4], kv[4];
            #pragma unroll
            for (int i = 0; i < 4; ++i) qv[i] = *(const float4*)&Qs[tr * 4 + i][d];
            #pragma unroll
            for (int j = 0; j < 4; ++j) kv[j] = *(const float4*)&Ks[tc + 16 * j][d];
            #pragma unroll
            for (int i = 0; i < 4; ++i) {
                const float qa[4] = {qv[i].x, qv[i].y, qv[i].z, qv[i].w};
                #pragma unroll
                for (int j = 0; j < 4; ++j) {
                    const float ka[4] = {kv[j].x, kv[j].y, kv[j].z, kv[j].w};
                    s[i][j] = fmaf(qa[0], ka[0], s[i][j]);
                    s[i][j] = fmaf(qa[1], ka[1], s[i][j]);
                    s[i][j] = fmaf(qa[2], ka[2], s[i][j]);
                    s[i][j] = fmaf(qa[3], ka[3], s[i][j]);
                }
            }
        }

        // scale + causal mask (only diagonal tile needs masking)
        const bool diag = (tile == ntiles - 1);
        #pragma unroll
        for (int i = 0; i < 4; ++i)
            #pragma unroll
            for (int j = 0; j < 4; ++j) {
                float sv = s[i][j] * scale;
                if (diag && (tc + 16 * j > tr * 4 + i)) sv = -3.0e38f;
                s[i][j] = sv;
            }

        // online softmax: row max / sum across the 16 lanes sharing tr
        float alpha[4], rsum[4];
        #pragma unroll
        for (int i = 0; i < 4; ++i) {
            float v = fmaxf(fmaxf(s[i][0], s[i][1]), fmaxf(s[i][2], s[i][3]));
            v = fmaxf(v, __shfl_xor(v, 1));
            v = fmaxf(v, __shfl_xor(v, 2));
            v = fmaxf(v, __shfl_xor(v, 4));
            v = fmaxf(v, __shfl_xor(v, 8));
            const float mn = fmaxf(m_i[i], v);
            alpha[i] = __expf(m_i[i] - mn);
            m_i[i]   = mn;
        }
        #pragma unroll
        for (int i = 0; i < 4; ++i) {
            float rs_ = 0.f;
            #pragma unroll
            for (int j = 0; j < 4; ++j) {
                const float p = __expf(s[i][j] - m_i[i]);
                s[i][j] = p;
                rs_ += p;
            }
            rs_ += __shfl_xor(rs_, 1);
            rs_ += __shfl_xor(rs_, 2);
            rs_ += __shfl_xor(rs_, 4);
            rs_ += __shfl_xor(rs_, 8);
            rsum[i] = rs_;
        }
        #pragma unroll
        for (int i = 0; i < 4; ++i) {
            l_i[i] = l_i[i] * alpha[i] + rsum[i];
            #pragma unroll
            for (int j = 0; j < 4; ++j) Oacc[i][j] *= alpha[i];
        }

        // publish P
        #pragma unroll
        for (int i = 0; i < 4; ++i)
            #pragma unroll
            for (int j = 0; j < 4; ++j)
                Ps[tr * 4 + i][tc + 16 * j] = s[i][j];
        __syncthreads();

        // O += P V
        #pragma unroll 4
        for (int c = 0; c < 64; c += 4) {
            float4 pvv[4], vv[4];
            #pragma unroll
            for (int i = 0; i < 4; ++i) pvv[i] = *(const float4*)&Ps[tr * 4 + i][c];
            #pragma unroll
            for (int u = 0; u < 4; ++u) vv[u] = *(const float4*)&Vs[c + u][tc * 4];
            #pragma unroll
            for (int i = 0; i < 4; ++i) {
                const float pa[4] = {pvv[i].x, pvv[i].y, pvv[i].z, pvv[i].w};
                #pragma unroll
                for (int u = 0; u < 4; ++u) {
                    const float va[4] = {vv[u].x, vv[u].y, vv[u].z, vv[u].w};
                    #pragma unroll
                    for (int j = 0; j < 4; ++j)
                        Oacc[i][j] = fmaf(pa[u], va[j], Oacc[i][j]);
                }
            }
        }
        __syncthreads();
    }

    // epilogue: O /= l, write [S][NH*HD]
    #pragma unroll
    for (int i = 0; i < 4; ++i) {
        const float inv = 1.f / l_i[i];
        float4 o = {Oacc[i][0] * inv, Oacc[i][1] * inv,
                    Oacc[i][2] * inv, Oacc[i][3] * inv};
        *(float4*)(Aout + (size_t)(q0 + tr * 4 + i) * QCOLS + h * HD + tc * 4) = o;
    }
}

// ---------------------------------------------------------------------------
// Kernel 4: output projection.  out[2048x1024] = attn[2048x1024] @ Wo[1024x1024]
// ---------------------------------------------------------------------------
__global__ __launch_bounds__(256) void gemm_out_kernel(
    const float* __restrict__ A, const float* __restrict__ Wo,
    float* __restrict__ out)
{
    __shared__ float At[32][68];
    __shared__ float Bs[32][68];

    const int t  = threadIdx.x;
    const int m0 = blockIdx.x * 64;
    const int n0 = blockIdx.y * 64;

    const int tr = t >> 4, tc = t & 15;
    const int ar = t >> 3;
    const int ak = (t & 7) * 4;
    const int bk = t >> 3;
    const int bn = (t & 7) * 8;

    float acc[4][4] = {{0.f}};

    for (int k0 = 0; k0 < QCOLS; k0 += 32) {
        #pragma unroll
        for (int rr = 0; rr < 2; ++rr) {
            const int row = ar + rr * 32;
            float4 a = *(const float4*)(A + (size_t)(m0 + row) * QCOLS + k0 + ak);
            At[ak + 0][row] = a.x; At[ak + 1][row] = a.y;
            At[ak + 2][row] = a.z; At[ak + 3][row] = a.w;
        }
        {
            const float* src = Wo + (size_t)(k0 + bk) * D_MODEL + n0 + bn;
            float4 b0 = *(const float4*)(src);
            float4 b1 = *(const float4*)(src + 4);
            *(float4*)&Bs[bk][bn]     = b0;
            *(float4*)&Bs[bk][bn + 4] = b1;
        }
        __syncthreads();

        #pragma unroll
        for (int kk = 0; kk < 32; ++kk) {
            float4 a = *(const float4*)&At[kk][tr * 4];
            float4 b = *(const float4*)&Bs[kk][tc * 4];
            const float av[4] = {a.x, a.y, a.z, a.w};
            const float bv[4] = {b.x, b.y, b.z, b.w};
            #pragma unroll
            for (int i = 0; i < 4; ++i)
                #pragma unroll
                for (int j = 0; j < 4; ++j)
                    acc[i][j] = fmaf(av[i], bv[j], acc[i][j]);
        }
        __syncthreads();
    }

    #pragma unroll
    for (int i = 0; i < 4; ++i) {
        float4 o = {acc[i][0], acc[i][1], acc[i][2], acc[i][3]};
        *(float4*)(out + (size_t)(m0 + tr * 4 + i) * D_MODEL + n0 + tc * 4) = o;
    }
}

// ---------------------------------------------------------------------------
extern "C" void kernel_launch(void* const* d_in, const int* in_sizes, int n_in,
                              void* d_out, int out_size, void* d_ws, size_t ws_size,
                              hipStream_t stream)
{
    const float* x  = (const float*)d_in[0];
    const float* rc = (const float*)d_in[1];
    const float* rs = (const float*)d_in[2];
    const float* Wq = (const float*)d_in[3];
    const float* Wk = (const float*)d_in[4];
    const float* Wv = (const float*)d_in[5];
    const float* Wo = (const float*)d_in[6];
    float* out = (float*)d_out;

    float* ws   = (float*)d_ws;
    float* Qws  = ws;                                    //  NH*S*HD = 2,097,152 f
    float* Kws  = Qws + (size_t)NH  * S_LEN * HD;        //  NKV*S*HD =  524,288 f
    float* Vws  = Kws + (size_t)NKV * S_LEN * HD;        //  NKV*S*HD =  524,288 f
    float* Attn = Vws + (size_t)NKV * S_LEN * HD;        //  S*QCOLS = 2,097,152 f
    // total 20 MB of workspace

    dim3 g1(S_LEN / 64, (QCOLS + 2 * KVCOLS) / 64);      // 32 x 24
    gemm_qkv_kernel<<<g1, 256, 0, stream>>>(x, Wq, Wk, Wv, Qws, Kws, Vws);

    const int rope_elems = (NH + NKV) * S_LEN * 32;      // 1,310,720
    rope_kernel<<<rope_elems / 256, 256, 0, stream>>>(Qws, Kws, rc, rs);

    dim3 g3(S_LEN / 64, NH);                             // 32 x 16
    attn_kernel<<<g3, 256, 0, stream>>>(Qws, Kws, Vws, Attn);

    dim3 g4(S_LEN / 64, QCOLS / 64);                     // 32 x 16
    gemm_out_kernel<<<g4, 256, 0, stream>>>(Attn, Wo, out);
}

// Round 2
// 196.132 us; speedup vs baseline: 2.6177x; 2.6177x over previous
//
#include <hip/hip_runtime.h>

typedef unsigned short ushort_t;
typedef __attribute__((ext_vector_type(8))) short short8;
typedef __attribute__((ext_vector_type(4))) float f32x4;
typedef __attribute__((ext_vector_type(4))) unsigned short ushort4v;
typedef __attribute__((ext_vector_type(8))) unsigned short ushort8v;

#define S_LEN 2048
#define D_MODEL 1024
#define NH 16
#define NKV 4
#define HD 64

// fp32 -> bf16 round-to-nearest-even
__device__ __forceinline__ ushort_t f2bf(float f) {
    unsigned u = __float_as_uint(f);
    u += 0x7fffu + ((u >> 16) & 1u);
    return (ushort_t)(u >> 16);
}

// async global->LDS, 16B per lane; lds base must be wave-uniform,
// HW scatters to lds + lane*16 (m97/m104 semantics)
__device__ __forceinline__ void cp16(void* lds, const void* g) {
    __builtin_amdgcn_global_load_lds(
        (__attribute__((address_space(1))) void*)g,
        (__attribute__((address_space(3))) void*)lds, 16, 0, 0);
}

// ---------------------------------------------------------------------------
// x fp32 [2048][1024] -> bf16 same layout
// ---------------------------------------------------------------------------
__global__ __launch_bounds__(256) void convert_x_kernel(
    const float* __restrict__ x, ushort_t* __restrict__ xb)
{
    const int i = (blockIdx.x * 256 + threadIdx.x) * 4;
    float4 v = *(const float4*)(x + i);
    ushort4v o = { f2bf(v.x), f2bf(v.y), f2bf(v.z), f2bf(v.w) };
    *(ushort4v*)(xb + i) = o;
}

// ---------------------------------------------------------------------------
// Weight transpose+cast: W[k][n] fp32 -> WT[n][k] bf16 (row stride K=1024).
// grid (K/64, maxN/64, 4); 64x64 tile through LDS.
// ---------------------------------------------------------------------------
__global__ __launch_bounds__(256) void wtrans_kernel(
    const float* __restrict__ Wq, const float* __restrict__ Wk,
    const float* __restrict__ Wv, const float* __restrict__ Wo,
    ushort_t* __restrict__ WqT, ushort_t* __restrict__ WkT,
    ushort_t* __restrict__ WvT, ushort_t* __restrict__ WoT)
{
    __shared__ ushort_t T[64 * 72];
    const float* W; ushort_t* WT; int N;
    switch (blockIdx.z) {
        case 0:  W = Wq; WT = WqT; N = 1024; break;
        case 1:  W = Wk; WT = WkT; N = 256;  break;
        case 2:  W = Wv; WT = WvT; N = 256;  break;
        default: W = Wo; WT = WoT; N = 1024; break;
    }
    const int n0 = blockIdx.y * 64;
    if (n0 >= N) return;
    const int k0 = blockIdx.x * 64;
    const int t  = threadIdx.x;
    const int kr = t >> 4, nc = (t & 15) * 4;
    #pragma unroll
    for (int p = 0; p < 4; ++p) {
        const int k = kr + p * 16;
        float4 v = *(const float4*)(W + (size_t)(k0 + k) * N + n0 + nc);
        T[(nc + 0) * 72 + k] = f2bf(v.x);
        T[(nc + 1) * 72 + k] = f2bf(v.y);
        T[(nc + 2) * 72 + k] = f2bf(v.z);
        T[(nc + 3) * 72 + k] = f2bf(v.w);
    }
    __syncthreads();
    const int n = t >> 2, seg = (t & 3) * 16;
    ushort8v a = *(ushort8v*)&T[n * 72 + seg];
    ushort8v b = *(ushort8v*)&T[n * 72 + seg + 8];
    *(ushort8v*)(WT + (size_t)(n0 + n) * 1024 + k0 + seg)     = a;
    *(ushort8v*)(WT + (size_t)(n0 + n) * 1024 + k0 + seg + 8) = b;
}

// ---------------------------------------------------------------------------
// QKV projection, bf16 MFMA, 128x128 tile, BK=32, 4 waves (2x2 of 64x64).
// Fused RoPE epilogue; Q/K head-major bf16, V transposed [kvh][d][s] bf16.
// grid (16, 12): cy 0..7 -> Q, 8..9 -> K, 10..11 -> V.
// ---------------------------------------------------------------------------
__global__ __launch_bounds__(256) void gemm_qkv_mfma(
    const ushort_t* __restrict__ xb, const ushort_t* __restrict__ WqT,
    const ushort_t* __restrict__ WkT, const ushort_t* __restrict__ WvT,
    const float* __restrict__ rc, const float* __restrict__ rs,
    ushort_t* __restrict__ Qb, ushort_t* __restrict__ Kb,
    ushort_t* __restrict__ Vtb)
{
    __shared__ ushort_t As[128 * 32];
    __shared__ ushort_t Bs[128 * 32];

    const int t = threadIdx.x;
    const int lane = t & 63, wave = t >> 6;
    const int wr = wave >> 1, wc = wave & 1;
    const int quad = lane >> 4, l15 = lane & 15;

    const int m0 = blockIdx.x * 128;
    const int cy = blockIdx.y;

    const ushort_t* WT; int nloc;
    if (cy < 8)       { WT = WqT; nloc = cy * 128; }
    else if (cy < 10) { WT = WkT; nloc = (cy - 8) * 128; }
    else              { WT = WvT; nloc = (cy - 10) * 128; }

    const int srow = wave * 32 + (lane >> 2);   // staging row (+issue*16)
    const int sseg = (lane & 3) * 8;            // ushort col offset

    f32x4 acc[4][4];
    #pragma unroll
    for (int i = 0; i < 4; ++i)
        #pragma unroll
        for (int j = 0; j < 4; ++j) acc[i][j] = (f32x4)0.f;

    for (int k0 = 0; k0 < D_MODEL; k0 += 32) {
        #pragma unroll
        for (int issue = 0; issue < 2; ++issue) {
            const int r = srow + issue * 16;
            cp16(&As[(wave * 32 + issue * 16) * 32],
                 xb + (size_t)(m0 + r) * 1024 + k0 + sseg);
            cp16(&Bs[(wave * 32 + issue * 16) * 32],
                 WT + (size_t)(nloc + r) * 1024 + k0 + sseg);
        }
        __syncthreads();

        short8 bfr[4];
        #pragma unroll
        for (int j = 0; j < 4; ++j)
            bfr[j] = *(const short8*)&Bs[(wc * 64 + j * 16 + l15) * 32 + quad * 8];
        #pragma unroll
        for (int i = 0; i < 4; ++i) {
            short8 a = *(const short8*)&As[(wr * 64 + i * 16 + l15) * 32 + quad * 8];
            #pragma unroll
            for (int j = 0; j < 4; ++j)
                acc[i][j] = __builtin_amdgcn_mfma_f32_16x16x32_bf16(a, bfr[j], acc[i][j], 0, 0, 0);
        }
        __syncthreads();
    }

    // epilogue: C/D layout col = l15 (+16j), row = quad*4+reg (+16i)  [m89]
    if (cy < 10) {
        // Q or K with fused RoPE
        ushort_t* dst = (cy < 8) ? Qb : Kb;
        const int h = ((cy < 8) ? cy : (cy - 8)) * 2 + wc;
        #pragma unroll
        for (int i = 0; i < 4; ++i) {
            #pragma unroll
            for (int j = 0; j < 2; ++j) {
                const int d = j * 16 + l15;
                #pragma unroll
                for (int reg = 0; reg < 4; ++reg) {
                    const int s = m0 + wr * 64 + i * 16 + quad * 4 + reg;
                    const float c  = rc[s * 32 + d];
                    const float sn = rs[s * 32 + d];
                    const float v1 = acc[i][j][reg];
                    const float v2 = acc[i][j + 2][reg];
                    dst[((size_t)h * S_LEN + s) * HD + d]      = f2bf(v1 * c - v2 * sn);
                    dst[((size_t)h * S_LEN + s) * HD + d + 32] = f2bf(v2 * c + v1 * sn);
                }
            }
        }
    } else {
        // V transposed: Vtb[vh][d][s]
        const int vh = (cy - 10) * 2 + wc;
        #pragma unroll
        for (int i = 0; i < 4; ++i) {
            const int s0 = m0 + wr * 64 + i * 16 + quad * 4;
            #pragma unroll
            for (int j = 0; j < 4; ++j) {
                const int d = j * 16 + l15;
                ushort4v o = { f2bf(acc[i][j][0]), f2bf(acc[i][j][1]),
                               f2bf(acc[i][j][2]), f2bf(acc[i][j][3]) };
                *(ushort4v*)&Vtb[((size_t)vh * HD + d) * S_LEN + s0] = o;
            }
        }
    }
}

// ---------------------------------------------------------------------------
// MFMA flash attention. grid (NH, 32): snake q-tile map for causal balance.
// Block = 4 waves; wave w owns q rows w*16..+15 of the 64-row tile.
// ---------------------------------------------------------------------------
__global__ __launch_bounds__(256) void attn_mfma(
    const ushort_t* __restrict__ Qb, const ushort_t* __restrict__ Kb,
    const ushort_t* __restrict__ Vtb, ushort_t* __restrict__ attnb)
{
    __shared__ ushort_t Qs[64 * 64];
    __shared__ ushort_t Ks[64 * 64];
    __shared__ ushort_t Vs[64 * 64];          // Vs[d][kv_local]
    __shared__ ushort_t Ps[4][16 * 72];       // per-wave P, stride 72

    const int t = threadIdx.x;
    const int lane = t & 63, wave = t >> 6;
    const int quad = lane >> 4, l15 = lane & 15;

    const int h  = blockIdx.x;
    const int y  = blockIdx.y;
    const int qt = (y < 16) ? y : 47 - y;     // pairs (y, y+16) -> 33 tiles/CU
    const int q0 = qt * 64;
    const int kvh = h >> 2;                   // GQA group

    const ushort_t* Qg = Qb + ((size_t)h * S_LEN + q0) * HD;
    const ushort_t* Kg = Kb + (size_t)kvh * S_LEN * HD;
    const ushort_t* Vg = Vtb + (size_t)kvh * HD * S_LEN;

    const int srow = wave * 16 + (lane >> 3);  // staging row (+issue*8)
    const int sseg = (lane & 7) * 8;           // ushort col offset

    #pragma unroll
    for (int issue = 0; issue < 2; ++issue)
        cp16(&Qs[(wave * 16 + issue * 8) * 64],
             Qg + (size_t)(srow + issue * 8) * HD + sseg);
    __syncthreads();

    // A-frags of Q (hoisted): lane holds A[m=l15][k=quad*8+j]  [m120]
    short8 aq0 = *(const short8*)&Qs[(wave * 16 + l15) * 64 + quad * 8];
    short8 aq1 = *(const short8*)&Qs[(wave * 16 + l15) * 64 + 32 + quad * 8];

    float m_i[4], l_i[4];
    f32x4 Oacc[4];
    #pragma unroll
    for (int r = 0; r < 4; ++r) { m_i[r] = -3.0e38f; l_i[r] = 0.f; }
    #pragma unroll
    for (int jb = 0; jb < 4; ++jb) Oacc[jb] = (f32x4)0.f;

    const int ntiles = qt + 1;
    for (int tile = 0; tile < ntiles; ++tile) {
        const int kv0 = tile * 64;
        __syncthreads();                       // prior reads of Ks/Vs complete
        #pragma unroll
        for (int issue = 0; issue < 2; ++issue) {
            cp16(&Ks[(wave * 16 + issue * 8) * 64],
                 Kg + (size_t)(kv0 + srow + issue * 8) * HD + sseg);
            cp16(&Vs[(wave * 16 + issue * 8) * 64],
                 Vg + (size_t)(srow + issue * 8) * S_LEN + kv0 + sseg);
        }
        __syncthreads();

        // S = Q K^T : B-frag reads K rows contiguous (B[k=d][n=kv] = K[kv][d])
        f32x4 sv[4];
        #pragma unroll
        for (int jb = 0; jb < 4; ++jb) {
            short8 b0 = *(const short8*)&Ks[(jb * 16 + l15) * 64 + quad * 8];
            short8 b1 = *(const short8*)&Ks[(jb * 16 + l15) * 64 + 32 + quad * 8];
            f32x4 z = (f32x4)0.f;
            z = __builtin_amdgcn_mfma_f32_16x16x32_bf16(aq0, b0, z, 0, 0, 0);
            z = __builtin_amdgcn_mfma_f32_16x16x32_bf16(aq1, b1, z, 0, 0, 0);
            sv[jb] = z;
        }

        // scale + causal mask (only the diagonal tile crosses the boundary)
        const bool diag = (tile == ntiles - 1);
        #pragma unroll
        for (int jb = 0; jb < 4; ++jb) {
            const int col = kv0 + jb * 16 + l15;
            #pragma unroll
            for (int reg = 0; reg < 4; ++reg) {
                const int row = q0 + wave * 16 + quad * 4 + reg;
                float xv = sv[jb][reg] * 0.125f;
                if (diag && col > row) xv = -3.0e38f;
                sv[jb][reg] = xv;
            }
        }

        // online softmax: row r lives in 16 lanes of quad r>>2, reg r&3
        float alpha[4];
        #pragma unroll
        for (int reg = 0; reg < 4; ++reg) {
            float mx = fmaxf(fmaxf(sv[0][reg], sv[1][reg]),
                             fmaxf(sv[2][reg], sv[3][reg]));
            mx = fmaxf(mx, __shfl_xor(mx, 1));
            mx = fmaxf(mx, __shfl_xor(mx, 2));
            mx = fmaxf(mx, __shfl_xor(mx, 4));
            mx = fmaxf(mx, __shfl_xor(mx, 8));
            const float mn = fmaxf(m_i[reg], mx);
            alpha[reg] = __expf(m_i[reg] - mn);
            m_i[reg] = mn;
            float rs_ = 0.f;
            #pragma unroll
            for (int jb = 0; jb < 4; ++jb) {
                const float p = __expf(sv[jb][reg] - mn);
                sv[jb][reg] = p;
                rs_ += p;
            }
            rs_ += __shfl_xor(rs_, 1);
            rs_ += __shfl_xor(rs_, 2);
            rs_ += __shfl_xor(rs_, 4);
            rs_ += __shfl_xor(rs_, 8);
            l_i[reg] = l_i[reg] * alpha[reg] + rs_;
        }
        #pragma unroll
        for (int jb = 0; jb < 4; ++jb)
            #pragma unroll
            for (int reg = 0; reg < 4; ++reg)
                Oacc[jb][reg] *= alpha[reg];

        // P: C-layout regs -> wave-private LDS -> A-layout frags  [m120]
        ushort_t* Pw = &Ps[wave][0];
        #pragma unroll
        for (int jb = 0; jb < 4; ++jb)
            #pragma unroll
            for (int reg = 0; reg < 4; ++reg)
                Pw[(quad * 4 + reg) * 72 + jb * 16 + l15] = f2bf(sv[jb][reg]);

        short8 p0 = *(const short8*)&Pw[l15 * 72 + quad * 8];
        short8 p1 = *(const short8*)&Pw[l15 * 72 + 32 + quad * 8];

        // O += P V : B-frag = V[kv][d] read from Vs[d][kv] rows (contiguous)
        #pragma unroll
        for (int jb = 0; jb < 4; ++jb) {
            short8 v0 = *(const short8*)&Vs[(jb * 16 + l15) * 64 + quad * 8];
            short8 v1 = *(const short8*)&Vs[(jb * 16 + l15) * 64 + 32 + quad * 8];
            Oacc[jb] = __builtin_amdgcn_mfma_f32_16x16x32_bf16(p0, v0, Oacc[jb], 0, 0, 0);
            Oacc[jb] = __builtin_amdgcn_mfma_f32_16x16x32_bf16(p1, v1, Oacc[jb], 0, 0, 0);
        }
    }

    // epilogue: attnb[s][h*64+d] bf16
    #pragma unroll
    for (int reg = 0; reg < 4; ++reg) {
        const float inv = 1.f / l_i[reg];
        const int s = q0 + wave * 16 + quad * 4 + reg;
        #pragma unroll
        for (int jb = 0; jb < 4; ++jb)
            attnb[(size_t)s * D_MODEL + h * HD + jb * 16 + l15] =
                f2bf(Oacc[jb][reg] * inv);
    }
}

// ---------------------------------------------------------------------------
// Output projection, bf16 MFMA, fp32 out. grid (16, 8).
// ---------------------------------------------------------------------------
__global__ __launch_bounds__(256) void gemm_out_mfma(
    const ushort_t* __restrict__ Ab, const ushort_t* __restrict__ WoT,
    float* __restrict__ out)
{
    __shared__ ushort_t As[128 * 32];
    __shared__ ushort_t Bs[128 * 32];

    const int t = threadIdx.x;
    const int lane = t & 63, wave = t >> 6;
    const int wr = wave >> 1, wc = wave & 1;
    const int quad = lane >> 4, l15 = lane & 15;

    const int m0 = blockIdx.x * 128;
    const int n0 = blockIdx.y * 128;

    const int srow = wave * 32 + (lane >> 2);
    const int sseg = (lane & 3) * 8;

    f32x4 acc[4][4];
    #pragma unroll
    for (int i = 0; i < 4; ++i)
        #pragma unroll
        for (int j = 0; j < 4; ++j) acc[i][j] = (f32x4)0.f;

    for (int k0 = 0; k0 < D_MODEL; k0 += 32) {
        #pragma unroll
        for (int issue = 0; issue < 2; ++issue) {
            const int r = srow + issue * 16;
            cp16(&As[(wave * 32 + issue * 16) * 32],
                 Ab + (size_t)(m0 + r) * 1024 + k0 + sseg);
            cp16(&Bs[(wave * 32 + issue * 16) * 32],
                 WoT + (size_t)(n0 + r) * 1024 + k0 + sseg);
        }
        __syncthreads();

        short8 bfr[4];
        #pragma unroll
        for (int j = 0; j < 4; ++j)
            bfr[j] = *(const short8*)&Bs[(wc * 64 + j * 16 + l15) * 32 + quad * 8];
        #pragma unroll
        for (int i = 0; i < 4; ++i) {
            short8 a = *(const short8*)&As[(wr * 64 + i * 16 + l15) * 32 + quad * 8];
            #pragma unroll
            for (int j = 0; j < 4; ++j)
                acc[i][j] = __builtin_amdgcn_mfma_f32_16x16x32_bf16(a, bfr[j], acc[i][j], 0, 0, 0);
        }
        __syncthreads();
    }

    #pragma unroll
    for (int i = 0; i < 4; ++i)
        #pragma unroll
        for (int reg = 0; reg < 4; ++reg) {
            const int s = m0 + wr * 64 + i * 16 + quad * 4 + reg;
            #pragma unroll
            for (int j = 0; j < 4; ++j)
                out[(size_t)s * D_MODEL + n0 + wc * 64 + j * 16 + l15] = acc[i][j][reg];
        }
}

// ---------------------------------------------------------------------------
extern "C" void kernel_launch(void* const* d_in, const int* in_sizes, int n_in,
                              void* d_out, int out_size, void* d_ws, size_t ws_size,
                              hipStream_t stream)
{
    const float* x  = (const float*)d_in[0];
    const float* rc = (const float*)d_in[1];
    const float* rs = (const float*)d_in[2];
    const float* Wq = (const float*)d_in[3];
    const float* Wk = (const float*)d_in[4];
    const float* Wv = (const float*)d_in[5];
    const float* Wo = (const float*)d_in[6];
    float* out = (float*)d_out;

    // bf16 workspace layout (ushort elements), 19 MB total
    ushort_t* xb   = (ushort_t*)d_ws;                          // 2048*1024
    ushort_t* WqT  = xb   + (size_t)2048 * 1024;               // 1024*1024
    ushort_t* WkT  = WqT  + (size_t)1024 * 1024;               //  256*1024
    ushort_t* WvT  = WkT  + (size_t)256 * 1024;                //  256*1024
    ushort_t* WoT  = WvT  + (size_t)256 * 1024;                // 1024*1024
    ushort_t* Qb   = WoT  + (size_t)1024 * 1024;               // 16*2048*64
    ushort_t* Kb   = Qb   + (size_t)NH * S_LEN * HD;           //  4*2048*64
    ushort_t* Vtb  = Kb   + (size_t)NKV * S_LEN * HD;          //  4*64*2048
    ushort_t* attnb= Vtb  + (size_t)NKV * HD * S_LEN;          // 2048*1024

    convert_x_kernel<<<2048, 256, 0, stream>>>(x, xb);
    wtrans_kernel<<<dim3(16, 16, 4), 256, 0, stream>>>(Wq, Wk, Wv, Wo,
                                                       WqT, WkT, WvT, WoT);
    gemm_qkv_mfma<<<dim3(16, 12), 256, 0, stream>>>(xb, WqT, WkT, WvT,
                                                    rc, rs, Qb, Kb, Vtb);
    attn_mfma<<<dim3(NH, 32), 256, 0, stream>>>(Qb, Kb, Vtb, attnb);
    gemm_out_mfma<<<dim3(16, 8), 256, 0, stream>>>(attnb, WoT, out);
}